// Round 1
// baseline (473.001 us; speedup 1.0000x reference)
//
#include <hip/hip_runtime.h>
#include <cstdint>
#include <cstddef>

typedef unsigned short u16;
using bf16x8 = __attribute__((ext_vector_type(8))) short;
using f32x4  = __attribute__((ext_vector_type(4))) float;

#define MFMA16(a, b, c) __builtin_amdgcn_mfma_f32_16x16x32_bf16((a), (b), (c), 0, 0, 0)

__device__ __forceinline__ u16 f2bf(float f) {
  union { float f; unsigned u; } x; x.f = f;
  unsigned r = x.u + 0x7fffu + ((x.u >> 16) & 1u);
  return (u16)(r >> 16);
}
__device__ __forceinline__ float bf2f(u16 h) {
  union { unsigned u; float f; } x; x.u = ((unsigned)h) << 16;
  return x.f;
}
__device__ __forceinline__ void gll16(const void* g, void* l) {
  __builtin_amdgcn_global_load_lds((const __attribute__((address_space(1))) void*)g,
                                   (__attribute__((address_space(3))) void*)l, 16, 0, 0);
}

union U8 { bf16x8 v; u16 u[8]; };

// ---------------- fp32 -> bf16 cast ----------------
__global__ __launch_bounds__(256) void cvt_kernel(const float* __restrict__ in,
                                                  u16* __restrict__ out, int n4) {
  int i = blockIdx.x * blockDim.x + threadIdx.x;
  if (i >= n4) return;
  float4 v = ((const float4*)in)[i];
  ushort4 o;
  o.x = f2bf(v.x); o.y = f2bf(v.y); o.z = f2bf(v.z); o.w = f2bf(v.w);
  ((ushort4*)out)[i] = o;
}

// ---------------- 256x256 NT GEMM, 3-stage counted-vmcnt pipeline ----------------
// C = A * B^T + bias. A [M][K] bf16, Bw [N][K] bf16, bias [N] f32.
// 512 thr = 8 waves (2M x 4N), per-wave 128x64 output, BK=32.
// LDS: 3 buffers x (256x32) x {A,B} = 96 KiB -> 1 block/CU, 8 waves.
// Schedule per K-tile t (2 phases):
//   ph1: ds_read af[0..3]+bfr[0..3] | STAGE_A(t+2) | barrier | setprio(1) 16xMFMA
//   ph2: ds_read af[4..7]           | STAGE_B(t+2) | barrier | setprio(1) 16xMFMA
//   end: s_waitcnt vmcnt(4)  (t+1 confirmed, t+2's 4 loads stay in flight) | barrier
// Race-freedom: a stage for tile t+2 targets buf[(t+2)%3], whose last readers
// (tile t-1) finished before the group-(t-1)-end barrier; the group-end vmcnt
// carries a "memory" clobber so the compiler cannot hoist next-tile ds_reads.
// LDS swizzle (T2): linear gll dest + pre-swizzled GLOBAL slot + swizzled read,
// involution slot ^= (row>>1)&3 -> 16B bank-groups go 8-way -> 2-way (free).
__global__ __launch_bounds__(512, 2) void gemm_bt256(const u16* __restrict__ A,
                                                     const u16* __restrict__ Bw,
                                                     const float* __restrict__ bias,
                                                     void* __restrict__ Cout,
                                                     int M, int N, int K, int out_bf16) {
  __shared__ u16 As[3][8192];
  __shared__ u16 Bs[3][8192];
  const int tid = threadIdx.x;
  const int lane = tid & 63, wave = tid >> 6;
  const int col = lane & 15, quad = lane >> 4;
  const int wr = wave >> 2, wc = wave & 3;
  const int bm = blockIdx.y, bn = blockIdx.x;
  const u16* Ag = A + (size_t)bm * 256 * K;
  const u16* Bg = Bw + (size_t)bn * 256 * K;
  // staging: 16B chunk l in {tid, tid+512}: row=l>>2, lds slot=l&3,
  // global slot = slot ^ ((row>>1)&3)  (same involution as the read side)
  const int r0 = tid >> 2, r1 = (tid + 512) >> 2;
  const int sl = tid & 3;
  const size_t off0 = (size_t)r0 * K + ((sl ^ ((r0 >> 1) & 3)) << 3);
  const size_t off1 = (size_t)r1 * K + ((sl ^ ((r1 >> 1) & 3)) << 3);
  f32x4 acc[8][4] = {};
  const int NT = K >> 5;

#define STAGE_A(buf, k0) do { \
    gll16(Ag + off0 + (k0), (void*)(As[buf] + tid * 8)); \
    gll16(Ag + off1 + (k0), (void*)(As[buf] + 4096 + tid * 8)); } while (0)
#define STAGE_B(buf, k0) do { \
    gll16(Bg + off0 + (k0), (void*)(Bs[buf] + tid * 8)); \
    gll16(Bg + off1 + (k0), (void*)(Bs[buf] + 4096 + tid * 8)); } while (0)

  // prologue: tiles 0 and 1 in flight; confirm tile 0, keep tile 1 outstanding
  STAGE_A(0, 0); STAGE_B(0, 0);
  if (NT > 1) {
    STAGE_A(1, 32); STAGE_B(1, 32);
    asm volatile("s_waitcnt vmcnt(4)" ::: "memory");
  } else {
    asm volatile("s_waitcnt vmcnt(0)" ::: "memory");
  }
  __builtin_amdgcn_s_barrier();

  int cur = 0;
  for (int t = 0; t < NT; ++t) {
    const u16* Ab = As[cur];
    const u16* Bb = Bs[cur];
    int nx2 = cur + 2; if (nx2 >= 3) nx2 -= 3;
    const bool pf = (t + 2) < NT;
    const int k2 = (t + 2) << 5;
    bf16x8 af[4], bfr[4];
    // ---- phase 1: C-half 1 (Mfrags 0..3 x Nfrags 0..3) ----
#pragma unroll
    for (int i = 0; i < 4; i++) {
      const int row = wr * 128 + i * 16 + col;
      af[i] = *(const bf16x8*)&Ab[row * 32 + ((quad ^ ((row >> 1) & 3)) << 3)];
    }
#pragma unroll
    for (int j = 0; j < 4; j++) {
      const int row = wc * 64 + j * 16 + col;
      bfr[j] = *(const bf16x8*)&Bb[row * 32 + ((quad ^ ((row >> 1) & 3)) << 3)];
    }
    if (pf) STAGE_A(nx2, k2);
    __builtin_amdgcn_s_barrier();
    __builtin_amdgcn_s_setprio(1);
#pragma unroll
    for (int i = 0; i < 4; i++)
#pragma unroll
      for (int j = 0; j < 4; j++)
        acc[i][j] = MFMA16(af[i], bfr[j], acc[i][j]);
    __builtin_amdgcn_s_setprio(0);
    __builtin_amdgcn_s_barrier();
    // ---- phase 2: C-half 2 (Mfrags 4..7 x Nfrags 0..3, bfr reused) ----
#pragma unroll
    for (int i = 0; i < 4; i++) {
      const int row = wr * 128 + (i + 4) * 16 + col;
      af[i] = *(const bf16x8*)&Ab[row * 32 + ((quad ^ ((row >> 1) & 3)) << 3)];
    }
    if (pf) STAGE_B(nx2, k2);
    __builtin_amdgcn_s_barrier();
    __builtin_amdgcn_s_setprio(1);
#pragma unroll
    for (int i = 0; i < 4; i++)
#pragma unroll
      for (int j = 0; j < 4; j++)
        acc[4 + i][j] = MFMA16(af[i], bfr[j], acc[4 + i][j]);
    __builtin_amdgcn_s_setprio(0);
    // group end: confirm tile t+1; keep tile t+2's 4 loads in flight
    if (pf) asm volatile("s_waitcnt vmcnt(4)" ::: "memory");
    else    asm volatile("s_waitcnt vmcnt(0)" ::: "memory");
    __builtin_amdgcn_s_barrier();
    cur = (cur + 1 == 3) ? 0 : cur + 1;
  }

  // epilogue
#pragma unroll
  for (int i = 0; i < 8; i++) {
    const int row0 = bm * 256 + wr * 128 + i * 16 + quad * 4;
#pragma unroll
    for (int j = 0; j < 4; j++) {
      const int cn = bn * 256 + wc * 64 + j * 16 + col;
      const float bv = bias[cn];
#pragma unroll
      for (int r = 0; r < 4; r++) {
        float v = acc[i][j][r] + bv;
        size_t off = (size_t)(row0 + r) * N + cn;
        if (out_bf16) ((u16*)Cout)[off] = f2bf(v);
        else          ((float*)Cout)[off] = v;
      }
    }
  }
#undef STAGE_A
#undef STAGE_B
}

// ---------------- RoPE + reorder + V transpose ----------------
// qkv [B*T][6144] bf16 -> q,k [bh][2048][128] bf16 (q pre-scaled by 1/sqrt(128)),
// vt [bh][128][2048] bf16.  grid (bh=32, tb=32), block 256.
__global__ __launch_bounds__(256) void rope_kernel(const u16* __restrict__ qkv,
                                                   const float* __restrict__ cosT,
                                                   const float* __restrict__ sinT,
                                                   u16* __restrict__ qo,
                                                   u16* __restrict__ ko,
                                                   u16* __restrict__ vt) {
  __shared__ u16 vs[128 * 72];
  const int bh = blockIdx.x;
  const int b = bh >> 4, h = bh & 15;
  const int tb = blockIdx.y;
  const int tid = threadIdx.x;
  const int tl = tid >> 2;        // 0..63
  const int g = tid & 3;
  const int t = tb * 64 + tl;
  const size_t qrow = ((size_t)(b * 2048 + t)) * 6144 + h * 128;
  const size_t orow = ((size_t)bh * 2048 + t) * 128;
  const int tt = t * 128;
  const int dl = g * 16, dh = 64 + dl;
  const float scale = 0.08838834764831845f;  // 1/sqrt(128)
#pragma unroll
  for (int cch = 0; cch < 2; cch++) {
    const int o8 = cch * 8;
    U8 ql, qh, kl, kh, vl, vh;
    ql.v = *(const bf16x8*)&qkv[qrow + dl + o8];
    qh.v = *(const bf16x8*)&qkv[qrow + dh + o8];
    kl.v = *(const bf16x8*)&qkv[qrow + 2048 + dl + o8];
    kh.v = *(const bf16x8*)&qkv[qrow + 2048 + dh + o8];
    vl.v = *(const bf16x8*)&qkv[qrow + 4096 + dl + o8];
    vh.v = *(const bf16x8*)&qkv[qrow + 4096 + dh + o8];
    float cl[8], ch_[8], sl[8], sh_[8];
    *(float4*)&cl[0]  = *(const float4*)&cosT[tt + dl + o8];
    *(float4*)&cl[4]  = *(const float4*)&cosT[tt + dl + o8 + 4];
    *(float4*)&ch_[0] = *(const float4*)&cosT[tt + dh + o8];
    *(float4*)&ch_[4] = *(const float4*)&cosT[tt + dh + o8 + 4];
    *(float4*)&sl[0]  = *(const float4*)&sinT[tt + dl + o8];
    *(float4*)&sl[4]  = *(const float4*)&sinT[tt + dl + o8 + 4];
    *(float4*)&sh_[0] = *(const float4*)&sinT[tt + dh + o8];
    *(float4*)&sh_[4] = *(const float4*)&sinT[tt + dh + o8 + 4];
    U8 aq, bq, ak, bk;
#pragma unroll
    for (int i = 0; i < 8; i++) {
      float qlf = bf2f(ql.u[i]), qhf = bf2f(qh.u[i]);
      float klf = bf2f(kl.u[i]), khf = bf2f(kh.u[i]);
      aq.u[i] = f2bf((qlf * cl[i]  - qhf * sl[i])  * scale);
      bq.u[i] = f2bf((qhf * ch_[i] + qlf * sh_[i]) * scale);
      ak.u[i] = f2bf(klf * cl[i]  - khf * sl[i]);
      bk.u[i] = f2bf(khf * ch_[i] + klf * sh_[i]);
    }
    *(bf16x8*)&qo[orow + dl + o8] = aq.v;
    *(bf16x8*)&qo[orow + dh + o8] = bq.v;
    *(bf16x8*)&ko[orow + dl + o8] = ak.v;
    *(bf16x8*)&ko[orow + dh + o8] = bk.v;
#pragma unroll
    for (int i = 0; i < 8; i++) {
      vs[(dl + o8 + i) * 72 + tl] = vl.u[i];
      vs[(dh + o8 + i) * 72 + tl] = vh.u[i];
    }
  }
  __syncthreads();
#pragma unroll
  for (int c = 0; c < 4; c++) {
    int idx = c * 256 + tid;
    int dd = idx >> 3, chk = idx & 7;
    bf16x8 vv = *(const bf16x8*)&vs[dd * 72 + chk * 8];
    *(bf16x8*)&vt[((size_t)bh * 128 + dd) * 2048 + tb * 64 + chk * 8] = vv;
  }
}

// ---------------- causal flash attention (no-max softmax) ----------------
// Q,K [bh][2048][128] bf16 (Q pre-scaled), Vt [bh][128][2048] bf16.
// O [B][T][H*128] bf16.
__global__ __launch_bounds__(256) void attn_kernel(const u16* __restrict__ Q,
                                                   const u16* __restrict__ Kk,
                                                   const u16* __restrict__ Vt,
                                                   u16* __restrict__ O) {
  __shared__ u16 Ks[64 * 136];       // 64 keys x 128 dims (+pad)
  __shared__ u16 Vs[128 * 72];       // 128 dims x 64 keys (+pad)
  __shared__ u16 Ps[4][16 * 72];     // per-wave P scratch: 16 q x 64 keys (+pad)
  const int bh = blockIdx.y, b = bh >> 4, h = bh & 15;
  const int qtile = gridDim.x - 1 - blockIdx.x;  // heavy blocks dispatch first
  const int qb = qtile * 128;
  const int tid = threadIdx.x, wave = tid >> 6, lane = tid & 63;
  const int col = lane & 15, quad = lane >> 4;
  const int qw0 = qb + wave * 32;    // wave owns rows [qw0, qw0+31]
  const int qw1 = qw0 + 16;
  const u16* Qg = Q + (size_t)bh * 2048 * 128;
  const u16* Kg = Kk + (size_t)bh * 2048 * 128;
  const u16* Vg = Vt + (size_t)bh * 128 * 2048;
  bf16x8 qf0[4], qf1[4];
#pragma unroll
  for (int c = 0; c < 4; c++) {
    qf0[c] = *(const bf16x8*)&Qg[(size_t)(qw0 + col) * 128 + c * 32 + quad * 8];
    qf1[c] = *(const bf16x8*)&Qg[(size_t)(qw1 + col) * 128 + c * 32 + quad * 8];
  }
  f32x4 o0[8] = {}, o1[8] = {};
  float ls0[4] = {0.f, 0.f, 0.f, 0.f}, ls1[4] = {0.f, 0.f, 0.f, 0.f};
  const int ntiles = (qb + 128) >> 6;
  const int kr = tid >> 2, kc = (tid & 3) * 8;  // K staging: 4 thr/row
  const int vr = tid >> 1, vc = (tid & 1) * 8;  // V staging: 2 thr/row
  for (int it = 0; it < ntiles; ++it) {
    const int kt = it << 6;
    __syncthreads();
#pragma unroll
    for (int u = 0; u < 4; u++)
      *(bf16x8*)&Ks[kr * 136 + kc + u * 32] =
          *(const bf16x8*)&Kg[(size_t)(kt + kr) * 128 + kc + u * 32];
#pragma unroll
    for (int u = 0; u < 4; u++)
      *(bf16x8*)&Vs[vr * 72 + vc + u * 16] =
          *(const bf16x8*)&Vg[(size_t)vr * 2048 + kt + vc + u * 16];
    __syncthreads();
    if (kt > qw1 + 15) continue;     // wave-uniform; barriers stay matched
    const bool do0 = (kt <= qw0 + 15);
    f32x4 s0[4] = {}, s1[4] = {};
#pragma unroll
    for (int c = 0; c < 4; c++) {
#pragma unroll
      for (int kg = 0; kg < 4; kg++) {
        bf16x8 kf = *(const bf16x8*)&Ks[(kg * 16 + col) * 136 + c * 32 + quad * 8];
        s0[kg] = MFMA16(qf0[c], kf, s0[kg]);
        s1[kg] = MFMA16(qf1[c], kf, s1[kg]);
      }
    }
    u16* pw = Ps[wave];
    if (do0) {  // q-tile 0: exp+mask, P->LDS->A-frag, PV
#pragma unroll
      for (int kg = 0; kg < 4; kg++)
#pragma unroll
        for (int r = 0; r < 4; r++) {
          int key = kt + kg * 16 + col, qg = qw0 + quad * 4 + r;
          float p = (key <= qg) ? __expf(s0[kg][r]) : 0.f;
          ls0[r] += p;
          pw[(quad * 4 + r) * 72 + kg * 16 + col] = f2bf(p);
        }
#pragma unroll
      for (int ks = 0; ks < 64; ks += 32) {
        bf16x8 pf = *(const bf16x8*)&pw[col * 72 + ks + quad * 8];
#pragma unroll
        for (int dt = 0; dt < 8; dt++) {
          bf16x8 vf = *(const bf16x8*)&Vs[(dt * 16 + col) * 72 + ks + quad * 8];
          o0[dt] = MFMA16(pf, vf, o0[dt]);
        }
      }
    }
    {  // q-tile 1
#pragma unroll
      for (int kg = 0; kg < 4; kg++)
#pragma unroll
        for (int r = 0; r < 4; r++) {
          int key = kt + kg * 16 + col, qg = qw1 + quad * 4 + r;
          float p = (key <= qg) ? __expf(s1[kg][r]) : 0.f;
          ls1[r] += p;
          pw[(quad * 4 + r) * 72 + kg * 16 + col] = f2bf(p);
        }
#pragma unroll
      for (int ks = 0; ks < 64; ks += 32) {
        bf16x8 pf = *(const bf16x8*)&pw[col * 72 + ks + quad * 8];
#pragma unroll
        for (int dt = 0; dt < 8; dt++) {
          bf16x8 vf = *(const bf16x8*)&Vs[(dt * 16 + col) * 72 + ks + quad * 8];
          o1[dt] = MFMA16(pf, vf, o1[dt]);
        }
      }
    }
  }
  // single end-of-kernel row-sum reduction across the 16 cols
#pragma unroll
  for (int st = 1; st < 16; st <<= 1)
#pragma unroll
    for (int r = 0; r < 4; r++) {
      ls0[r] += __shfl_xor(ls0[r], st);
      ls1[r] += __shfl_xor(ls1[r], st);
    }
#pragma unroll
  for (int r = 0; r < 4; r++) {
    float inv0 = 1.0f / ls0[r], inv1 = 1.0f / ls1[r];
    size_t row0 = ((size_t)(b * 2048 + qw0 + quad * 4 + r)) * 2048 + h * 128;
    size_t row1 = ((size_t)(b * 2048 + qw1 + quad * 4 + r)) * 2048 + h * 128;
#pragma unroll
    for (int dt = 0; dt < 8; dt++) {
      O[row0 + dt * 16 + col] = f2bf(o0[dt][r] * inv0);
      O[row1 + dt * 16 + col] = f2bf(o1[dt][r] * inv1);
    }
  }
}

// ---------------- launch ----------------
extern "C" void kernel_launch(void* const* d_in, const int* in_sizes, int n_in,
                              void* d_out, int out_size, void* d_ws, size_t ws_size,
                              hipStream_t stream) {
  const float* x        = (const float*)d_in[0];  // [2,2048,2048]
  const float* rope_cos = (const float*)d_in[1];  // [1,1,2048,128]
  const float* rope_sin = (const float*)d_in[2];
  const float* qkv_w    = (const float*)d_in[3];  // [6144,2048]
  const float* qkv_b    = (const float*)d_in[4];  // [6144]
  const float* out_w    = (const float*)d_in[5];  // [2048,2048]
  const float* out_b    = (const float*)d_in[6];  // [2048]
  float* out = (float*)d_out;
  u16* ws = (u16*)d_ws;
  u16* xb    = ws;                  //  8388608 elems  (x bf16)
  u16* wqkvb = xb + 8388608;        // 12582912 elems
  u16* woutb = wqkvb + 12582912;    //  4194304 elems
  u16* qkvb  = woutb + 4194304;     // 25165824 elems
  u16* qb    = qkvb + 25165824;     //  8388608 elems
  u16* kb    = qb + 8388608;        //  8388608 elems
  u16* vtb   = kb + 8388608;        //  8388608 elems
  u16* attnb = xb;                  // reuse: xb dead after QKV GEMM

  cvt_kernel<<<8192, 256, 0, stream>>>(x, xb, 2097152);
  cvt_kernel<<<12288, 256, 0, stream>>>(qkv_w, wqkvb, 3145728);
  cvt_kernel<<<4096, 256, 0, stream>>>(out_w, woutb, 1048576);
  // qkv = x * qkv_w^T + qkv_b  -> bf16 [4096][6144]
  gemm_bt256<<<dim3(24, 16), 512, 0, stream>>>(xb, wqkvb, qkv_b, qkvb, 4096, 6144, 2048, 1);
  // rope + reorder + v-transpose
  rope_kernel<<<dim3(32, 32), 256, 0, stream>>>(qkvb, rope_cos, rope_sin, qb, kb, vtb);
  // causal flash attention -> bf16 [B,T,D]
  attn_kernel<<<dim3(16, 32), 256, 0, stream>>>(qb, kb, vtb, attnb);
  // out = attn * out_w^T + out_b -> f32 d_out
  gemm_bt256<<<dim3(8, 16), 512, 0, stream>>>(attnb, woutb, out_b, out, 4096, 2048, 2048, 0);
}

// Round 2
// 448.754 us; speedup vs baseline: 1.0540x; 1.0540x over previous
//
#include <hip/hip_runtime.h>
#include <cstdint>
#include <cstddef>

typedef unsigned short u16;
using bf16x8 = __attribute__((ext_vector_type(8))) short;
using f32x4  = __attribute__((ext_vector_type(4))) float;

#define MFMA16(a, b, c) __builtin_amdgcn_mfma_f32_16x16x32_bf16((a), (b), (c), 0, 0, 0)

__device__ __forceinline__ u16 f2bf(float f) {
  union { float f; unsigned u; } x; x.f = f;
  unsigned r = x.u + 0x7fffu + ((x.u >> 16) & 1u);
  return (u16)(r >> 16);
}
__device__ __forceinline__ float bf2f(u16 h) {
  union { unsigned u; float f; } x; x.u = ((unsigned)h) << 16;
  return x.f;
}
__device__ __forceinline__ void gll16(const void* g, void* l) {
  __builtin_amdgcn_global_load_lds((const __attribute__((address_space(1))) void*)g,
                                   (__attribute__((address_space(3))) void*)l, 16, 0, 0);
}

union U8 { bf16x8 v; u16 u[8]; };

// ---------------- fp32 -> bf16 cast ----------------
__global__ __launch_bounds__(256) void cvt_kernel(const float* __restrict__ in,
                                                  u16* __restrict__ out, int n4) {
  int i = blockIdx.x * blockDim.x + threadIdx.x;
  if (i >= n4) return;
  float4 v = ((const float4*)in)[i];
  ushort4 o;
  o.x = f2bf(v.x); o.y = f2bf(v.y); o.z = f2bf(v.z); o.w = f2bf(v.w);
  ((ushort4*)out)[i] = o;
}

// ---------------- 256x256 NT GEMM, overlapped 1-barrier/tile pipeline ----------------
// C = A * B^T + bias. A [M][K] bf16, Bw [N][K] bf16, bias [N] f32.
// 512 thr = 8 waves (2M x 4N), per-wave 128x64 output, BK=32, NT = K/32 (even).
// LDS: 4 buffers x 16KiB(A) + 4 x 16KiB(B) = 128 KiB -> 1 block/CU, 8 waves.
// Per tile t (ONE barrier):
//   a: ds_read af2 = frags(t,ph2)          [4 reads]   \  drain overlaps (c)
//   b: STAGE_A(t+2)                        [2 gll]      |
//   c: MFMA ph1(t): acc[0..3][j] += afC[i]*bfC[j]       /
//   d: vmcnt(2) + s_barrier                -- confirms A(t+1),B(t+1); publishes t+1
//   e: ds_read frags(t+1,ph1) -> ping-pong set  [8 reads]  \ drain overlaps (g)
//   f: STAGE_B(t+2)                        [2 gll]           |
//   g: MFMA ph2(t): acc[4..7][j] += af2[i]*bfC[j]           /
// Ledger (per-thread outstanding at d): {A(t+1)2, B(t+1)2, A(t+2)2} -> vmcnt(2)
// confirms exactly tile t+1. Write-after-read: stage of t+2 into buf[(t+2)&3]
// happens >= 1 barrier after that buffer's last read (read at t-2, consumed
// before (t-1).d barrier). Tail: stages guarded by t+2<NT, wait drops to vmcnt(0).
__global__ __launch_bounds__(512, 2) void gemm_bt256(const u16* __restrict__ A,
                                                     const u16* __restrict__ Bw,
                                                     const float* __restrict__ bias,
                                                     void* __restrict__ Cout,
                                                     int M, int N, int K, int out_bf16) {
  __shared__ u16 As[4][8192];
  __shared__ u16 Bs[4][8192];
  const int tid = threadIdx.x;
  const int lane = tid & 63, wave = tid >> 6;
  const int col = lane & 15, quad = lane >> 4;
  const int wr = wave >> 2, wc = wave & 3;
  const int bm = blockIdx.y, bn = blockIdx.x;
  const u16* Ag = A + (size_t)bm * 256 * K;
  const u16* Bg = Bw + (size_t)bn * 256 * K;
  // staging: 16B chunk l in {tid, tid+512}: row=l>>2, lds slot=l&3,
  // global slot = slot ^ ((row>>1)&3)  (same involution as the read side)
  const int r0 = tid >> 2, r1 = (tid + 512) >> 2;
  const int sl = tid & 3;
  const size_t off0 = (size_t)r0 * K + ((sl ^ ((r0 >> 1) & 3)) << 3);
  const size_t off1 = (size_t)r1 * K + ((sl ^ ((r1 >> 1) & 3)) << 3);
  f32x4 acc[8][4] = {};
  const int NT = K >> 5;
  // swizzled read offsets (u16 elems), loop-invariant
  int ra1[4], ra2[4], rb[4];
#pragma unroll
  for (int i = 0; i < 4; i++) {
    int r1_ = wr * 128 + i * 16 + col;
    int r2_ = r1_ + 64;
    int rb_ = wc * 64 + i * 16 + col;
    ra1[i] = r1_ * 32 + ((quad ^ ((r1_ >> 1) & 3)) << 3);
    ra2[i] = r2_ * 32 + ((quad ^ ((r2_ >> 1) & 3)) << 3);
    rb[i]  = rb_ * 32 + ((quad ^ ((rb_ >> 1) & 3)) << 3);
  }

#define STAGE_A(bi, k0) do { \
    gll16(Ag + off0 + (k0), (void*)(As[bi] + tid * 8)); \
    gll16(Ag + off1 + (k0), (void*)(As[bi] + 4096 + tid * 8)); } while (0)
#define STAGE_B(bi, k0) do { \
    gll16(Bg + off0 + (k0), (void*)(Bs[bi] + tid * 8)); \
    gll16(Bg + off1 + (k0), (void*)(Bs[bi] + 4096 + tid * 8)); } while (0)

#define TILE_STEP(AF, BF, AFN, BFN, TT)                                        \
  do {                                                                         \
    const u16* Ab_ = As[(TT) & 3];                                             \
    _Pragma("unroll")                                                          \
    for (int i_ = 0; i_ < 4; i_++) af2[i_] = *(const bf16x8*)&Ab_[ra2[i_]];    \
    if ((TT) + 2 < NT) STAGE_A(((TT) + 2) & 3, ((TT) + 2) << 5);               \
    __builtin_amdgcn_s_setprio(1);                                             \
    _Pragma("unroll")                                                          \
    for (int i_ = 0; i_ < 4; i_++)                                             \
      _Pragma("unroll")                                                        \
      for (int j_ = 0; j_ < 4; j_++)                                           \
        acc[i_][j_] = MFMA16(AF[i_], BF[j_], acc[i_][j_]);                     \
    __builtin_amdgcn_s_setprio(0);                                             \
    if ((TT) + 2 < NT) { asm volatile("s_waitcnt vmcnt(2)" ::: "memory"); }    \
    else               { asm volatile("s_waitcnt vmcnt(0)" ::: "memory"); }    \
    __builtin_amdgcn_s_barrier();                                              \
    if ((TT) + 1 < NT) {                                                       \
      const u16* An_ = As[((TT) + 1) & 3];                                     \
      const u16* Bn_ = Bs[((TT) + 1) & 3];                                     \
      _Pragma("unroll")                                                        \
      for (int i_ = 0; i_ < 4; i_++) {                                         \
        AFN[i_] = *(const bf16x8*)&An_[ra1[i_]];                               \
        BFN[i_] = *(const bf16x8*)&Bn_[rb[i_]];                                \
      }                                                                        \
    }                                                                          \
    if ((TT) + 2 < NT) STAGE_B(((TT) + 2) & 3, ((TT) + 2) << 5);               \
    __builtin_amdgcn_s_setprio(1);                                             \
    _Pragma("unroll")                                                          \
    for (int i_ = 0; i_ < 4; i_++)                                             \
      _Pragma("unroll")                                                        \
      for (int j_ = 0; j_ < 4; j_++)                                           \
        acc[4 + i_][j_] = MFMA16(af2[i_], BF[j_], acc[4 + i_][j_]);            \
    __builtin_amdgcn_s_setprio(0);                                             \
  } while (0)

  // prologue: stage tile0 fully + A(1); confirm tile0; read frags(0,ph1); stage B(1)
  STAGE_A(0, 0); STAGE_B(0, 0); STAGE_A(1, 32);
  asm volatile("s_waitcnt vmcnt(2)" ::: "memory");
  __builtin_amdgcn_s_barrier();
  bf16x8 afX[4], bfX[4], afY[4], bfY[4], af2[4];
#pragma unroll
  for (int i = 0; i < 4; i++) {
    afX[i] = *(const bf16x8*)&As[0][ra1[i]];
    bfX[i] = *(const bf16x8*)&Bs[0][rb[i]];
  }
  STAGE_B(1, 32);

  for (int t = 0; t < NT; t += 2) {
    TILE_STEP(afX, bfX, afY, bfY, t);
    TILE_STEP(afY, bfY, afX, bfX, t + 1);
  }

  // epilogue
#pragma unroll
  for (int i = 0; i < 8; i++) {
    const int row0 = bm * 256 + wr * 128 + i * 16 + quad * 4;
#pragma unroll
    for (int j = 0; j < 4; j++) {
      const int cn = bn * 256 + wc * 64 + j * 16 + col;
      const float bv = bias[cn];
#pragma unroll
      for (int r = 0; r < 4; r++) {
        float v = acc[i][j][r] + bv;
        size_t off = (size_t)(row0 + r) * N + cn;
        if (out_bf16) ((u16*)Cout)[off] = f2bf(v);
        else          ((float*)Cout)[off] = v;
      }
    }
  }
#undef STAGE_A
#undef STAGE_B
#undef TILE_STEP
}

// ---------------- RoPE + reorder + V transpose ----------------
// qkv [B*T][6144] bf16 -> q,k [bh][2048][128] bf16 (q pre-scaled by 1/sqrt(128)),
// vt [bh][128][2048] bf16.  grid (bh=32, tb=32), block 256.
__global__ __launch_bounds__(256) void rope_kernel(const u16* __restrict__ qkv,
                                                   const float* __restrict__ cosT,
                                                   const float* __restrict__ sinT,
                                                   u16* __restrict__ qo,
                                                   u16* __restrict__ ko,
                                                   u16* __restrict__ vt) {
  __shared__ u16 vs[128 * 72];
  const int bh = blockIdx.x;
  const int b = bh >> 4, h = bh & 15;
  const int tb = blockIdx.y;
  const int tid = threadIdx.x;
  const int tl = tid >> 2;        // 0..63
  const int g = tid & 3;
  const int t = tb * 64 + tl;
  const size_t qrow = ((size_t)(b * 2048 + t)) * 6144 + h * 128;
  const size_t orow = ((size_t)bh * 2048 + t) * 128;
  const int tt = t * 128;
  const int dl = g * 16, dh = 64 + dl;
  const float scale = 0.08838834764831845f;  // 1/sqrt(128)
#pragma unroll
  for (int cch = 0; cch < 2; cch++) {
    const int o8 = cch * 8;
    U8 ql, qh, kl, kh, vl, vh;
    ql.v = *(const bf16x8*)&qkv[qrow + dl + o8];
    qh.v = *(const bf16x8*)&qkv[qrow + dh + o8];
    kl.v = *(const bf16x8*)&qkv[qrow + 2048 + dl + o8];
    kh.v = *(const bf16x8*)&qkv[qrow + 2048 + dh + o8];
    vl.v = *(const bf16x8*)&qkv[qrow + 4096 + dl + o8];
    vh.v = *(const bf16x8*)&qkv[qrow + 4096 + dh + o8];
    float cl[8], ch_[8], sl[8], sh_[8];
    *(float4*)&cl[0]  = *(const float4*)&cosT[tt + dl + o8];
    *(float4*)&cl[4]  = *(const float4*)&cosT[tt + dl + o8 + 4];
    *(float4*)&ch_[0] = *(const float4*)&cosT[tt + dh + o8];
    *(float4*)&ch_[4] = *(const float4*)&cosT[tt + dh + o8 + 4];
    *(float4*)&sl[0]  = *(const float4*)&sinT[tt + dl + o8];
    *(float4*)&sl[4]  = *(const float4*)&sinT[tt + dl + o8 + 4];
    *(float4*)&sh_[0] = *(const float4*)&sinT[tt + dh + o8];
    *(float4*)&sh_[4] = *(const float4*)&sinT[tt + dh + o8 + 4];
    U8 aq, bq, ak, bk;
#pragma unroll
    for (int i = 0; i < 8; i++) {
      float qlf = bf2f(ql.u[i]), qhf = bf2f(qh.u[i]);
      float klf = bf2f(kl.u[i]), khf = bf2f(kh.u[i]);
      aq.u[i] = f2bf((qlf * cl[i]  - qhf * sl[i])  * scale);
      bq.u[i] = f2bf((qhf * ch_[i] + qlf * sh_[i]) * scale);
      ak.u[i] = f2bf(klf * cl[i]  - khf * sl[i]);
      bk.u[i] = f2bf(khf * ch_[i] + klf * sh_[i]);
    }
    *(bf16x8*)&qo[orow + dl + o8] = aq.v;
    *(bf16x8*)&qo[orow + dh + o8] = bq.v;
    *(bf16x8*)&ko[orow + dl + o8] = ak.v;
    *(bf16x8*)&ko[orow + dh + o8] = bk.v;
#pragma unroll
    for (int i = 0; i < 8; i++) {
      vs[(dl + o8 + i) * 72 + tl] = vl.u[i];
      vs[(dh + o8 + i) * 72 + tl] = vh.u[i];
    }
  }
  __syncthreads();
#pragma unroll
  for (int c = 0; c < 4; c++) {
    int idx = c * 256 + tid;
    int dd = idx >> 3, chk = idx & 7;
    bf16x8 vv = *(const bf16x8*)&vs[dd * 72 + chk * 8];
    *(bf16x8*)&vt[((size_t)bh * 128 + dd) * 2048 + tb * 64 + chk * 8] = vv;
  }
}

// ---------------- causal flash attention (no-max softmax) ----------------
// Q,K [bh][2048][128] bf16 (Q pre-scaled), Vt [bh][128][2048] bf16.
// O [B][T][H*128] bf16.
__global__ __launch_bounds__(256) void attn_kernel(const u16* __restrict__ Q,
                                                   const u16* __restrict__ Kk,
                                                   const u16* __restrict__ Vt,
                                                   u16* __restrict__ O) {
  __shared__ u16 Ks[64 * 136];       // 64 keys x 128 dims (+pad)
  __shared__ u16 Vs[128 * 72];       // 128 dims x 64 keys (+pad)
  __shared__ u16 Ps[4][16 * 72];     // per-wave P scratch: 16 q x 64 keys (+pad)
  const int bh = blockIdx.y, b = bh >> 4, h = bh & 15;
  const int qtile = gridDim.x - 1 - blockIdx.x;  // heavy blocks dispatch first
  const int qb = qtile * 128;
  const int tid = threadIdx.x, wave = tid >> 6, lane = tid & 63;
  const int col = lane & 15, quad = lane >> 4;
  const int qw0 = qb + wave * 32;    // wave owns rows [qw0, qw0+31]
  const int qw1 = qw0 + 16;
  const u16* Qg = Q + (size_t)bh * 2048 * 128;
  const u16* Kg = Kk + (size_t)bh * 2048 * 128;
  const u16* Vg = Vt + (size_t)bh * 128 * 2048;
  bf16x8 qf0[4], qf1[4];
#pragma unroll
  for (int c = 0; c < 4; c++) {
    qf0[c] = *(const bf16x8*)&Qg[(size_t)(qw0 + col) * 128 + c * 32 + quad * 8];
    qf1[c] = *(const bf16x8*)&Qg[(size_t)(qw1 + col) * 128 + c * 32 + quad * 8];
  }
  f32x4 o0[8] = {}, o1[8] = {};
  float ls0[4] = {0.f, 0.f, 0.f, 0.f}, ls1[4] = {0.f, 0.f, 0.f, 0.f};
  const int ntiles = (qb + 128) >> 6;
  const int kr = tid >> 2, kc = (tid & 3) * 8;  // K staging: 4 thr/row
  const int vr = tid >> 1, vc = (tid & 1) * 8;  // V staging: 2 thr/row
  for (int it = 0; it < ntiles; ++it) {
    const int kt = it << 6;
    __syncthreads();
#pragma unroll
    for (int u = 0; u < 4; u++)
      *(bf16x8*)&Ks[kr * 136 + kc + u * 32] =
          *(const bf16x8*)&Kg[(size_t)(kt + kr) * 128 + kc + u * 32];
#pragma unroll
    for (int u = 0; u < 4; u++)
      *(bf16x8*)&Vs[vr * 72 + vc + u * 16] =
          *(const bf16x8*)&Vg[(size_t)vr * 2048 + kt + vc + u * 16];
    __syncthreads();
    if (kt > qw1 + 15) continue;     // wave-uniform; barriers stay matched
    const bool do0 = (kt <= qw0 + 15);
    f32x4 s0[4] = {}, s1[4] = {};
#pragma unroll
    for (int c = 0; c < 4; c++) {
#pragma unroll
      for (int kg = 0; kg < 4; kg++) {
        bf16x8 kf = *(const bf16x8*)&Ks[(kg * 16 + col) * 136 + c * 32 + quad * 8];
        s0[kg] = MFMA16(qf0[c], kf, s0[kg]);
        s1[kg] = MFMA16(qf1[c], kf, s1[kg]);
      }
    }
    u16* pw = Ps[wave];
    if (do0) {  // q-tile 0: exp+mask, P->LDS->A-frag, PV
#pragma unroll
      for (int kg = 0; kg < 4; kg++)
#pragma unroll
        for (int r = 0; r < 4; r++) {
          int key = kt + kg * 16 + col, qg = qw0 + quad * 4 + r;
          float p = (key <= qg) ? __expf(s0[kg][r]) : 0.f;
          ls0[r] += p;
          pw[(quad * 4 + r) * 72 + kg * 16 + col] = f2bf(p);
        }
#pragma unroll
      for (int ks = 0; ks < 64; ks += 32) {
        bf16x8 pf = *(const bf16x8*)&pw[col * 72 + ks + quad * 8];
#pragma unroll
        for (int dt = 0; dt < 8; dt++) {
          bf16x8 vf = *(const bf16x8*)&Vs[(dt * 16 + col) * 72 + ks + quad * 8];
          o0[dt] = MFMA16(pf, vf, o0[dt]);
        }
      }
    }
    {  // q-tile 1
#pragma unroll
      for (int kg = 0; kg < 4; kg++)
#pragma unroll
        for (int r = 0; r < 4; r++) {
          int key = kt + kg * 16 + col, qg = qw1 + quad * 4 + r;
          float p = (key <= qg) ? __expf(s1[kg][r]) : 0.f;
          ls1[r] += p;
          pw[(quad * 4 + r) * 72 + kg * 16 + col] = f2bf(p);
        }
#pragma unroll
      for (int ks = 0; ks < 64; ks += 32) {
        bf16x8 pf = *(const bf16x8*)&pw[col * 72 + ks + quad * 8];
#pragma unroll
        for (int dt = 0; dt < 8; dt++) {
          bf16x8 vf = *(const bf16x8*)&Vs[(dt * 16 + col) * 72 + ks + quad * 8];
          o1[dt] = MFMA16(pf, vf, o1[dt]);
        }
      }
    }
  }
  // single end-of-kernel row-sum reduction across the 16 cols
#pragma unroll
  for (int st = 1; st < 16; st <<= 1)
#pragma unroll
    for (int r = 0; r < 4; r++) {
      ls0[r] += __shfl_xor(ls0[r], st);
      ls1[r] += __shfl_xor(ls1[r], st);
    }
#pragma unroll
  for (int r = 0; r < 4; r++) {
    float inv0 = 1.0f / ls0[r], inv1 = 1.0f / ls1[r];
    size_t row0 = ((size_t)(b * 2048 + qw0 + quad * 4 + r)) * 2048 + h * 128;
    size_t row1 = ((size_t)(b * 2048 + qw1 + quad * 4 + r)) * 2048 + h * 128;
#pragma unroll
    for (int dt = 0; dt < 8; dt++) {
      O[row0 + dt * 16 + col] = f2bf(o0[dt][r] * inv0);
      O[row1 + dt * 16 + col] = f2bf(o1[dt][r] * inv1);
    }
  }
}

// ---------------- launch ----------------
extern "C" void kernel_launch(void* const* d_in, const int* in_sizes, int n_in,
                              void* d_out, int out_size, void* d_ws, size_t ws_size,
                              hipStream_t stream) {
  const float* x        = (const float*)d_in[0];  // [2,2048,2048]
  const float* rope_cos = (const float*)d_in[1];  // [1,1,2048,128]
  const float* rope_sin = (const float*)d_in[2];
  const float* qkv_w    = (const float*)d_in[3];  // [6144,2048]
  const float* qkv_b    = (const float*)d_in[4];  // [6144]
  const float* out_w    = (const float*)d_in[5];  // [2048,2048]
  const float* out_b    = (const float*)d_in[6];  // [2048]
  float* out = (float*)d_out;
  u16* ws = (u16*)d_ws;
  u16* xb    = ws;                  //  8388608 elems  (x bf16)
  u16* wqkvb = xb + 8388608;        // 12582912 elems
  u16* woutb = wqkvb + 12582912;    //  4194304 elems
  u16* qkvb  = woutb + 4194304;     // 25165824 elems
  u16* qb    = qkvb + 25165824;     //  8388608 elems
  u16* kb    = qb + 8388608;        //  8388608 elems
  u16* vtb   = kb + 8388608;        //  8388608 elems
  u16* attnb = xb;                  // reuse: xb dead after QKV GEMM

  cvt_kernel<<<8192, 256, 0, stream>>>(x, xb, 2097152);
  cvt_kernel<<<12288, 256, 0, stream>>>(qkv_w, wqkvb, 3145728);
  cvt_kernel<<<4096, 256, 0, stream>>>(out_w, woutb, 1048576);
  // qkv = x * qkv_w^T + qkv_b  -> bf16 [4096][6144]
  gemm_bt256<<<dim3(24, 16), 512, 0, stream>>>(xb, wqkvb, qkv_b, qkvb, 4096, 6144, 2048, 1);
  // rope + reorder + v-transpose
  rope_kernel<<<dim3(32, 32), 256, 0, stream>>>(qkvb, rope_cos, rope_sin, qb, kb, vtb);
  // causal flash attention -> bf16 [B,T,D]
  attn_kernel<<<dim3(16, 32), 256, 0, stream>>>(qb, kb, vtb, attnb);
  // out = attn * out_w^T + out_b -> f32 d_out
  gemm_bt256<<<dim3(8, 16), 512, 0, stream>>>(attnb, woutb, out_b, out, 4096, 2048, 2048, 0);
}